// Round 1
// baseline (5446.766 us; speedup 1.0000x reference)
//
#include <hip/hip_runtime.h>
#include <hip/hip_bf16.h>
#include <math.h>

// HAN: word bi-GRU + attention -> sentence bi-GRU + attention -> doc vector.
// Strategy: split-bf16 (hi+lo) MFMA for all big GEMMs (f32-grade precision at
// 3x bf16-MFMA cost), f32 vector math for gates/attention.

typedef __attribute__((ext_vector_type(8))) short short8;
typedef __attribute__((ext_vector_type(4))) float f32x4;

__device__ __forceinline__ unsigned short f2bf(float f) {
    unsigned int u = __float_as_uint(f);
    u += 0x7fff + ((u >> 16) & 1);   // RNE
    return (unsigned short)(u >> 16);
}
__device__ __forceinline__ float bf2f(unsigned short u) {
    return __uint_as_float(((unsigned int)u) << 16);
}
__device__ __forceinline__ float sigmoidf_(float x) { return 1.f / (1.f + expf(-x)); }

__device__ __forceinline__ f32x4 mfma16(short8 a, short8 b, f32x4 c) {
    return __builtin_amdgcn_mfma_f32_16x16x32_bf16(a, b, c, 0, 0, 0);
}

// ---------------- split f32 -> (hi,lo) bf16 ----------------
__global__ __launch_bounds__(256) void split_f32(const float* __restrict__ src,
                                                 unsigned short* __restrict__ hi,
                                                 unsigned short* __restrict__ lo, int n) {
    int i = blockIdx.x * blockDim.x + threadIdx.x;
    int stride = gridDim.x * blockDim.x;
    for (; i < n; i += stride) {
        float v = src[i];
        unsigned short h = f2bf(v);
        hi[i] = h;
        lo[i] = f2bf(v - bf2f(h));
    }
}

// ---------------- split-bf16 MFMA GEMM (NT): C[m][n] = sum_k A[m][k]*B[n][k] + bias[n]
// A: f32 source, optional row gather via tokens. B: pre-split hi/lo bf16 [N][K].
// Block 256 thr (4 waves, 2x2), tile 64(M) x 128(N) x 32(K).
__global__ __launch_bounds__(256) void gemm_split(
    const float* __restrict__ A, const int* __restrict__ tokens,
    const unsigned short* __restrict__ Bhi, const unsigned short* __restrict__ Blo,
    const float* __restrict__ bias, float* __restrict__ C,
    int M, int N, int K)
{
    __shared__ unsigned short Ah[64][40], Al[64][40];    // pad 32->40 shorts (80B rows)
    __shared__ unsigned short Bh[128][40], Bl[128][40];

    int t = threadIdx.x;
    int m0 = blockIdx.x * 64, n0 = blockIdx.y * 128;
    int wave = t >> 6, lane = t & 63;
    int wm = wave >> 1, wn = wave & 1;
    int kg = lane >> 4, r16 = lane & 15;

    f32x4 acc[2][4];
#pragma unroll
    for (int i = 0; i < 2; i++)
#pragma unroll
        for (int j = 0; j < 4; j++)
#pragma unroll
            for (int q = 0; q < 4; q++) acc[i][j][q] = 0.f;

    // A staging role: thread -> (row, col8)
    int ar = t >> 2, ac8 = (t & 3) * 8;
    long arow = -1;
    if (m0 + ar < M) arow = tokens ? (long)tokens[m0 + ar] : (long)(m0 + ar);

    for (int kt = 0; kt < K; kt += 32) {
        // ---- stage A (f32 -> hi/lo in-register) ----
        {
            short8 hv, lv;
            if (arow >= 0) {
                const float* ap = A + arow * (long)K + kt + ac8;
                f32x4 u0 = *(const f32x4*)ap;
                f32x4 u1 = *(const f32x4*)(ap + 4);
#pragma unroll
                for (int i = 0; i < 8; i++) {
                    float x = (i < 4) ? u0[i] : u1[i - 4];
                    unsigned short hb = f2bf(x);
                    hv[i] = (short)hb;
                    lv[i] = (short)f2bf(x - bf2f(hb));
                }
            } else {
#pragma unroll
                for (int i = 0; i < 8; i++) { hv[i] = 0; lv[i] = 0; }
            }
            *(short8*)&Ah[ar][ac8] = hv;
            *(short8*)&Al[ar][ac8] = lv;
        }
        // ---- stage B (pre-split bf16, straight copy) ----
#pragma unroll
        for (int i = 0; i < 2; i++) {
            int idx = t + i * 256;          // 0..511 : 128 rows x 4 granules
            int br = idx >> 2, bc8 = (idx & 3) * 8;
            long go = (long)(n0 + br) * K + kt + bc8;
            *(short8*)&Bh[br][bc8] = *(const short8*)(Bhi + go);
            *(short8*)&Bl[br][bc8] = *(const short8*)(Blo + go);
        }
        __syncthreads();

        short8 afh[2], afl[2], bfh[4], bfl[4];
#pragma unroll
        for (int m16 = 0; m16 < 2; m16++) {
            afh[m16] = *(short8*)&Ah[wm * 32 + m16 * 16 + r16][kg * 8];
            afl[m16] = *(short8*)&Al[wm * 32 + m16 * 16 + r16][kg * 8];
        }
#pragma unroll
        for (int n16 = 0; n16 < 4; n16++) {
            bfh[n16] = *(short8*)&Bh[wn * 64 + n16 * 16 + r16][kg * 8];
            bfl[n16] = *(short8*)&Bl[wn * 64 + n16 * 16 + r16][kg * 8];
        }
#pragma unroll
        for (int m16 = 0; m16 < 2; m16++)
#pragma unroll
            for (int n16 = 0; n16 < 4; n16++) {
                acc[m16][n16] = mfma16(afh[m16], bfh[n16], acc[m16][n16]);
                acc[m16][n16] = mfma16(afh[m16], bfl[n16], acc[m16][n16]);
                acc[m16][n16] = mfma16(afl[m16], bfh[n16], acc[m16][n16]);
            }
        __syncthreads();
    }

    // epilogue: D row=(lane>>4)*4+q, col=lane&15  (verified layout)
#pragma unroll
    for (int m16 = 0; m16 < 2; m16++)
#pragma unroll
        for (int n16 = 0; n16 < 4; n16++)
#pragma unroll
            for (int q = 0; q < 4; q++) {
                int row = m0 + wm * 32 + m16 * 16 + kg * 4 + q;
                int col = n0 + wn * 64 + n16 * 16 + r16;
                if (row < M) C[(long)row * N + col] = acc[m16][n16][q] + bias[col];
            }
}

// ---------------- word GRU recurrent step (split-bf16 MFMA + fused gates) ----
// grid (6 batch-tiles of 32, 32 j-tiles of 32); block 192 thr = 3 waves (wave = gate).
__global__ __launch_bounds__(192) void word_step(
    const unsigned short* __restrict__ Whi, const unsigned short* __restrict__ Wlo, // [3072][1024]
    const unsigned short* __restrict__ hhi_in, const unsigned short* __restrict__ hlo_in,
    unsigned short* __restrict__ hhi_out, unsigned short* __restrict__ hlo_out,
    const float* __restrict__ xW, const float* __restrict__ bhh,
    float* __restrict__ bi, int tau)
{
    __shared__ unsigned short Ah[32][40], Al[32][40];
    __shared__ unsigned short Bh[96][40], Bl[96][40];
    __shared__ float gl[3][32][33];

    int t = threadIdx.x;
    int b0 = blockIdx.x * 32, j0 = blockIdx.y * 32;
    int g = t >> 6, lane = t & 63, kg = lane >> 4, r16 = lane & 15;

    f32x4 acc[2][2];
#pragma unroll
    for (int i = 0; i < 2; i++)
#pragma unroll
        for (int j = 0; j < 2; j++)
#pragma unroll
            for (int q = 0; q < 4; q++) acc[i][j][q] = 0.f;

    for (int kt = 0; kt < 1024; kt += 32) {
        // stage A (h hi/lo): 2 arrays x 32 rows x 4 granules = 256
        for (int idx = t; idx < 256; idx += 192) {
            int arr = idx >> 7, rem = idx & 127;
            int r = rem >> 2, c8 = (rem & 3) * 8;
            short8 v;
            if (tau > 0) {
                const unsigned short* src = (arr ? hlo_in : hhi_in) + (long)(b0 + r) * 1024 + kt + c8;
                v = *(const short8*)src;
            } else {
#pragma unroll
                for (int i = 0; i < 8; i++) v[i] = 0;
            }
            unsigned short (*P)[40] = arr ? Al : Ah;
            *(short8*)&P[r][c8] = v;
        }
        // stage B (Whh hi/lo): 2 x 96 x 4 = 768
#pragma unroll
        for (int i = 0; i < 4; i++) {
            int idx = t + i * 192;
            int arr = (idx >= 384) ? 1 : 0;
            int rem = idx - arr * 384;
            int r = rem >> 2, c8 = (rem & 3) * 8;
            int wrow = (r >> 5) * 1024 + j0 + (r & 31);
            const unsigned short* src = (arr ? Wlo : Whi) + (long)wrow * 1024 + kt + c8;
            unsigned short (*P)[40] = arr ? Bl : Bh;
            *(short8*)&P[r][c8] = *(const short8*)src;
        }
        __syncthreads();

        short8 ah[2], al[2], bh[2], blv[2];
#pragma unroll
        for (int m16 = 0; m16 < 2; m16++) {
            ah[m16] = *(short8*)&Ah[m16 * 16 + r16][kg * 8];
            al[m16] = *(short8*)&Al[m16 * 16 + r16][kg * 8];
        }
#pragma unroll
        for (int n16 = 0; n16 < 2; n16++) {
            bh[n16]  = *(short8*)&Bh[g * 32 + n16 * 16 + r16][kg * 8];
            blv[n16] = *(short8*)&Bl[g * 32 + n16 * 16 + r16][kg * 8];
        }
#pragma unroll
        for (int m16 = 0; m16 < 2; m16++)
#pragma unroll
            for (int n16 = 0; n16 < 2; n16++) {
                acc[m16][n16] = mfma16(ah[m16], bh[n16], acc[m16][n16]);
                acc[m16][n16] = mfma16(ah[m16], blv[n16], acc[m16][n16]);
                acc[m16][n16] = mfma16(al[m16], bh[n16], acc[m16][n16]);
            }
        __syncthreads();
    }

    // dump gate partials: [gate][batch-local][j-local]
#pragma unroll
    for (int m16 = 0; m16 < 2; m16++)
#pragma unroll
        for (int n16 = 0; n16 < 2; n16++)
#pragma unroll
            for (int q = 0; q < 4; q++)
                gl[g][m16 * 16 + kg * 4 + q][n16 * 16 + r16] = acc[m16][n16][q];
    __syncthreads();

    // fused gate epilogue
    for (int idx = t; idx < 1024; idx += 192) {
        int bloc = idx >> 5, jl = idx & 31;
        int b = b0 + bloc;
        int dir = (b >= 96) ? 1 : 0;
        int s = b - dir * 96;
        int pos = dir ? (95 - tau) : tau;
        int j = j0 + jl;
        const float* xp = xW + (long)(s * 96 + pos) * 3072;
        float hr = gl[0][bloc][jl] + bhh[j];
        float hz = gl[1][bloc][jl] + bhh[1024 + j];
        float hn = gl[2][bloc][jl] + bhh[2048 + j];
        float r = sigmoidf_(xp[j] + hr);
        float z = sigmoidf_(xp[1024 + j] + hz);
        float n = tanhf(xp[2048 + j] + r * hn);
        long o = (long)b * 1024 + j;
        float hprev = 0.f;
        if (tau > 0) hprev = bf2f(hhi_in[o]) + bf2f(hlo_in[o]);
        float hnew = (1.f - z) * n + z * hprev;
        unsigned short hh = f2bf(hnew);
        hhi_out[o] = hh;
        hlo_out[o] = f2bf(hnew - bf2f(hh));
        bi[(long)(s * 96 + pos) * 2048 + dir * 1024 + j] = hnew;
    }
}

// ---------------- word attention: sent_vecs[s] = sum_t exp(bi.wctx + b) * bi ----
__global__ __launch_bounds__(256) void word_attn(
    const float* __restrict__ bi, const float* __restrict__ wctx,
    const float* __restrict__ wctx_b, float* __restrict__ sent_vecs)
{
    __shared__ float red[4];
    int s = blockIdx.x, t = threadIdx.x;
    int c = t * 8;
    float wc[8], accv[8];
#pragma unroll
    for (int i = 0; i < 8; i++) { wc[i] = wctx[c + i]; accv[i] = 0.f; }
    float bb = wctx_b[0];
    int lane = t & 63, w = t >> 6;

    for (int tok = 0; tok < 96; tok++) {
        const float* row = bi + (long)(s * 96 + tok) * 2048 + c;
        float v[8];
        float p = 0.f;
#pragma unroll
        for (int i = 0; i < 8; i++) { v[i] = row[i]; p += v[i] * wc[i]; }
        p += __shfl_xor(p, 32); p += __shfl_xor(p, 16); p += __shfl_xor(p, 8);
        p += __shfl_xor(p, 4);  p += __shfl_xor(p, 2);  p += __shfl_xor(p, 1);
        __syncthreads();
        if (lane == 0) red[w] = p;
        __syncthreads();
        float sc = expf(red[0] + red[1] + red[2] + red[3] + bb);
#pragma unroll
        for (int i = 0; i < 8; i++) accv[i] += sc * v[i];
    }
#pragma unroll
    for (int i = 0; i < 8; i++) sent_vecs[(long)s * 2048 + c + i] = accv[i];
}

// ---------------- sentence GRU step (f32 vector; batch 2) ----
// grid 64 blocks (j-tile 16), 256 thr.
__global__ __launch_bounds__(256) void sent_step(
    const float* __restrict__ Whh, const float* __restrict__ xWs,
    const float* __restrict__ sbhh, const float* __restrict__ hs_in,
    float* __restrict__ hs_out, float* __restrict__ sbi, int tau)
{
    __shared__ float sh[2][1024];
    __shared__ float gdot[3][16][2];
    int t = threadIdx.x, j0 = blockIdx.x * 16;

    for (int idx = t; idx < 2048; idx += 256)
        sh[idx >> 10][idx & 1023] = (tau > 0) ? hs_in[idx] : 0.f;
    __syncthreads();

    if (t < 192) {
        int d = t >> 1, kq = t & 1;     // 96 dots x 2 k-halves
        int rr = d >> 1, bq = d & 1;    // rr 0..47 (3 gates x 16 j), bq batch
        int gg = rr >> 4, jl = rr & 15;
        int wrow = gg * 1024 + j0 + jl;
        const float* wp = Whh + (long)wrow * 1024 + kq * 512;
        const float* hp = &sh[bq][kq * 512];
        float acc = 0.f;
        for (int k = 0; k < 512; k += 4) {
            f32x4 wv = *(const f32x4*)(wp + k);
            f32x4 hv = *(const f32x4*)(hp + k);
            acc += wv[0] * hv[0] + wv[1] * hv[1] + wv[2] * hv[2] + wv[3] * hv[3];
        }
        acc += __shfl_xor(acc, 1);
        if (kq == 0) gdot[gg][jl][bq] = acc;
    }
    __syncthreads();

    if (t < 32) {
        int jl = t >> 1, bq = t & 1;
        int j = j0 + jl;
        int pos = bq ? (95 - tau) : tau;
        const float* xp = xWs + (long)pos * 3072;
        float r = sigmoidf_(xp[j] + gdot[0][jl][bq] + sbhh[j]);
        float z = sigmoidf_(xp[1024 + j] + gdot[1][jl][bq] + sbhh[1024 + j]);
        float n = tanhf(xp[2048 + j] + r * (gdot[2][jl][bq] + sbhh[2048 + j]));
        float hprev = (tau > 0) ? hs_in[bq * 1024 + j] : 0.f;
        float hnew = (1.f - z) * n + z * hprev;
        hs_out[bq * 1024 + j] = hnew;
        sbi[(long)pos * 2048 + bq * 1024 + j] = hnew;
    }
}

// ---------------- sentence attention ----
__global__ __launch_bounds__(256) void sent_scores(
    const float* __restrict__ sbi, const float* __restrict__ sctx,
    const float* __restrict__ sctx_b, float* __restrict__ scores)
{
    __shared__ float red[4];
    int s = blockIdx.x, t = threadIdx.x, c = t * 8;
    const float* row = sbi + (long)s * 2048 + c;
    float p = 0.f;
#pragma unroll
    for (int i = 0; i < 8; i++) p += row[i] * sctx[c + i];
    p += __shfl_xor(p, 32); p += __shfl_xor(p, 16); p += __shfl_xor(p, 8);
    p += __shfl_xor(p, 4);  p += __shfl_xor(p, 2);  p += __shfl_xor(p, 1);
    int lane = t & 63, w = t >> 6;
    if (lane == 0) red[w] = p;
    __syncthreads();
    if (t == 0) scores[s] = expf(red[0] + red[1] + red[2] + red[3] + sctx_b[0]);
}

__global__ __launch_bounds__(256) void doc_out(
    const float* __restrict__ sbi, const float* __restrict__ scores,
    float* __restrict__ out)
{
    int t = threadIdx.x, c = t * 8;
    float acc[8];
#pragma unroll
    for (int i = 0; i < 8; i++) acc[i] = 0.f;
    for (int s = 0; s < 96; s++) {
        float sc = scores[s];
        const float* row = sbi + (long)s * 2048 + c;
#pragma unroll
        for (int i = 0; i < 8; i++) acc[i] += sc * row[i];
    }
#pragma unroll
    for (int i = 0; i < 8; i++) out[c + i] = acc[i];
}

// ---------------- host ----------------
extern "C" void kernel_launch(void* const* d_in, const int* in_sizes, int n_in,
                              void* d_out, int out_size, void* d_ws, size_t ws_size,
                              hipStream_t stream)
{
    const int*   tokens    = (const int*)  d_in[0];
    const float* embedding = (const float*)d_in[1];
    const float* wWih = (const float*)d_in[2];
    const float* wWhh = (const float*)d_in[3];
    const float* wbih = (const float*)d_in[4];
    const float* wbhh = (const float*)d_in[5];
    const float* sWih = (const float*)d_in[6];
    const float* sWhh = (const float*)d_in[7];
    const float* sbih = (const float*)d_in[8];
    const float* sbhh = (const float*)d_in[9];
    const float* wctxw = (const float*)d_in[10];
    const float* wctxb = (const float*)d_in[11];
    const float* sctxw = (const float*)d_in[12];
    const float* sctxb = (const float*)d_in[13];
    float* out = (float*)d_out;

    char* p = (char*)d_ws;
    auto alloc = [&](size_t bytes) -> char* {
        char* r = p;
        p += (bytes + 255) & ~(size_t)255;
        return r;
    };
    unsigned short* WihHi  = (unsigned short*)alloc(3072l * 1024 * 2);
    unsigned short* WihLo  = (unsigned short*)alloc(3072l * 1024 * 2);
    unsigned short* WhhHi  = (unsigned short*)alloc(3072l * 1024 * 2);
    unsigned short* WhhLo  = (unsigned short*)alloc(3072l * 1024 * 2);
    unsigned short* sWihHi = (unsigned short*)alloc(3072l * 2048 * 2);
    unsigned short* sWihLo = (unsigned short*)alloc(3072l * 2048 * 2);
    float* xW        = (float*)alloc(9216l * 3072 * 4);
    float* bi        = (float*)alloc(9216l * 2048 * 4);
    unsigned short* hAhi = (unsigned short*)alloc(192l * 1024 * 2);
    unsigned short* hAlo = (unsigned short*)alloc(192l * 1024 * 2);
    unsigned short* hBhi = (unsigned short*)alloc(192l * 1024 * 2);
    unsigned short* hBlo = (unsigned short*)alloc(192l * 1024 * 2);
    float* sent_vecs = (float*)alloc(96l * 2048 * 4);
    float* xWs       = (float*)alloc(96l * 3072 * 4);
    float* hsA       = (float*)alloc(2l * 1024 * 4);
    float* hsB       = (float*)alloc(2l * 1024 * 4);
    float* sbi       = (float*)alloc(96l * 2048 * 4);
    float* scores    = (float*)alloc(512);
    (void)ws_size; (void)in_sizes; (void)n_in; (void)out_size;

    // one-time weight splits
    split_f32<<<1024, 256, 0, stream>>>(wWih, WihHi, WihLo, 3072 * 1024);
    split_f32<<<1024, 256, 0, stream>>>(wWhh, WhhHi, WhhLo, 3072 * 1024);
    split_f32<<<1024, 256, 0, stream>>>(sWih, sWihHi, sWihLo, 3072 * 2048);

    // word-level input projection (gather fused): xW = emb @ Wih^T + b_ih
    gemm_split<<<dim3(144, 24), 256, 0, stream>>>(
        embedding, tokens, WihHi, WihLo, wbih, xW, 9216, 3072, 1024);

    // word bi-GRU, 96 sequential steps (fwd+bwd batched: 192 sequences)
    for (int tau = 0; tau < 96; tau++) {
        const unsigned short *hi_in, *lo_in;
        unsigned short *hi_out, *lo_out;
        if (tau & 1) { hi_in = hAhi; lo_in = hAlo; hi_out = hBhi; lo_out = hBlo; }
        else         { hi_in = hBhi; lo_in = hBlo; hi_out = hAhi; lo_out = hAlo; }
        word_step<<<dim3(6, 32), 192, 0, stream>>>(
            WhhHi, WhhLo, hi_in, lo_in, hi_out, lo_out, xW, wbhh, bi, tau);
    }

    word_attn<<<96, 256, 0, stream>>>(bi, wctxw, wctxb, sent_vecs);

    // sentence input projection: xWs = sent_vecs @ sWih^T + s_bih
    gemm_split<<<dim3(2, 24), 256, 0, stream>>>(
        sent_vecs, nullptr, sWihHi, sWihLo, sbih, xWs, 96, 3072, 2048);

    // sentence bi-GRU, 96 steps, batch 2
    for (int tau = 0; tau < 96; tau++) {
        const float* hin; float* hout;
        if (tau & 1) { hin = hsA; hout = hsB; }
        else         { hin = hsB; hout = hsA; }
        sent_step<<<64, 256, 0, stream>>>(sWhh, xWs, sbhh, hin, hout, sbi, tau);
    }

    sent_scores<<<96, 256, 0, stream>>>(sbi, sctxw, sctxb, scores);
    doc_out<<<1, 256, 0, stream>>>(sbi, scores, out);
}

// Round 2
// 4536.132 us; speedup vs baseline: 1.2008x; 1.2008x over previous
//
#include <hip/hip_runtime.h>
#include <hip/hip_bf16.h>
#include <math.h>

// HAN: word bi-GRU + attention -> sentence bi-GRU + attention -> doc vector.
// Split-bf16 (hi+lo) MFMA for big GEMMs; f32 vector math for gates/attention.
// R1: word_step retiled -> 128 blocks, A-direct-to-reg, B via small LDS tile,
//     gate fusion in-register (n16 tile == gate). sent_step 4-way k-split.

typedef __attribute__((ext_vector_type(8))) short short8;
typedef __attribute__((ext_vector_type(4))) float f32x4;

__device__ __forceinline__ unsigned short f2bf(float f) {
    unsigned int u = __float_as_uint(f);
    u += 0x7fff + ((u >> 16) & 1);   // RNE
    return (unsigned short)(u >> 16);
}
__device__ __forceinline__ float bf2f(unsigned short u) {
    return __uint_as_float(((unsigned int)u) << 16);
}
__device__ __forceinline__ float sigmoidf_(float x) { return 1.f / (1.f + expf(-x)); }

__device__ __forceinline__ f32x4 mfma16(short8 a, short8 b, f32x4 c) {
    return __builtin_amdgcn_mfma_f32_16x16x32_bf16(a, b, c, 0, 0, 0);
}

// ---------------- split f32 -> (hi,lo) bf16 ----------------
__global__ __launch_bounds__(256) void split_f32(const float* __restrict__ src,
                                                 unsigned short* __restrict__ hi,
                                                 unsigned short* __restrict__ lo, int n) {
    int i = blockIdx.x * blockDim.x + threadIdx.x;
    int stride = gridDim.x * blockDim.x;
    for (; i < n; i += stride) {
        float v = src[i];
        unsigned short h = f2bf(v);
        hi[i] = h;
        lo[i] = f2bf(v - bf2f(h));
    }
}

// ---------------- split-bf16 MFMA GEMM (NT): C[m][n] = sum_k A[m][k]*B[n][k] + bias[n]
__global__ __launch_bounds__(256) void gemm_split(
    const float* __restrict__ A, const int* __restrict__ tokens,
    const unsigned short* __restrict__ Bhi, const unsigned short* __restrict__ Blo,
    const float* __restrict__ bias, float* __restrict__ C,
    int M, int N, int K)
{
    __shared__ unsigned short Ah[64][40], Al[64][40];
    __shared__ unsigned short Bh[128][40], Bl[128][40];

    int t = threadIdx.x;
    int m0 = blockIdx.x * 64, n0 = blockIdx.y * 128;
    int wave = t >> 6, lane = t & 63;
    int wm = wave >> 1, wn = wave & 1;
    int kg = lane >> 4, r16 = lane & 15;

    f32x4 acc[2][4];
#pragma unroll
    for (int i = 0; i < 2; i++)
#pragma unroll
        for (int j = 0; j < 4; j++)
#pragma unroll
            for (int q = 0; q < 4; q++) acc[i][j][q] = 0.f;

    int ar = t >> 2, ac8 = (t & 3) * 8;
    long arow = -1;
    if (m0 + ar < M) arow = tokens ? (long)tokens[m0 + ar] : (long)(m0 + ar);

    for (int kt = 0; kt < K; kt += 32) {
        {
            short8 hv, lv;
            if (arow >= 0) {
                const float* ap = A + arow * (long)K + kt + ac8;
                f32x4 u0 = *(const f32x4*)ap;
                f32x4 u1 = *(const f32x4*)(ap + 4);
#pragma unroll
                for (int i = 0; i < 8; i++) {
                    float x = (i < 4) ? u0[i] : u1[i - 4];
                    unsigned short hb = f2bf(x);
                    hv[i] = (short)hb;
                    lv[i] = (short)f2bf(x - bf2f(hb));
                }
            } else {
#pragma unroll
                for (int i = 0; i < 8; i++) { hv[i] = 0; lv[i] = 0; }
            }
            *(short8*)&Ah[ar][ac8] = hv;
            *(short8*)&Al[ar][ac8] = lv;
        }
#pragma unroll
        for (int i = 0; i < 2; i++) {
            int idx = t + i * 256;
            int br = idx >> 2, bc8 = (idx & 3) * 8;
            long go = (long)(n0 + br) * K + kt + bc8;
            *(short8*)&Bh[br][bc8] = *(const short8*)(Bhi + go);
            *(short8*)&Bl[br][bc8] = *(const short8*)(Blo + go);
        }
        __syncthreads();

        short8 afh[2], afl[2], bfh[4], bfl[4];
#pragma unroll
        for (int m16 = 0; m16 < 2; m16++) {
            afh[m16] = *(short8*)&Ah[wm * 32 + m16 * 16 + r16][kg * 8];
            afl[m16] = *(short8*)&Al[wm * 32 + m16 * 16 + r16][kg * 8];
        }
#pragma unroll
        for (int n16 = 0; n16 < 4; n16++) {
            bfh[n16] = *(short8*)&Bh[wn * 64 + n16 * 16 + r16][kg * 8];
            bfl[n16] = *(short8*)&Bl[wn * 64 + n16 * 16 + r16][kg * 8];
        }
#pragma unroll
        for (int m16 = 0; m16 < 2; m16++)
#pragma unroll
            for (int n16 = 0; n16 < 4; n16++) {
                acc[m16][n16] = mfma16(afh[m16], bfh[n16], acc[m16][n16]);
                acc[m16][n16] = mfma16(afh[m16], bfl[n16], acc[m16][n16]);
                acc[m16][n16] = mfma16(afl[m16], bfh[n16], acc[m16][n16]);
            }
        __syncthreads();
    }

#pragma unroll
    for (int m16 = 0; m16 < 2; m16++)
#pragma unroll
        for (int n16 = 0; n16 < 4; n16++)
#pragma unroll
            for (int q = 0; q < 4; q++) {
                int row = m0 + wm * 32 + m16 * 16 + kg * 4 + q;
                int col = n0 + wn * 64 + n16 * 16 + r16;
                if (row < M) C[(long)row * N + col] = acc[m16][n16][q] + bias[col];
            }
}

// ---------------- word GRU recurrent step v2 ----------------
// grid (2 m-tiles of 96, 64 j-tiles of 16); 192 thr = 3 waves.
// Wave w: rows m16 {2w, 2w+1}; cols = 3 n16 = the 3 gates of j-tile.
// A (h) fragments loaded direct global->reg; B (Whh) staged via 7.7KB LDS.
__global__ __launch_bounds__(192) void word_step2(
    const unsigned short* __restrict__ Whi, const unsigned short* __restrict__ Wlo,
    const unsigned short* __restrict__ hhi_in, const unsigned short* __restrict__ hlo_in,
    unsigned short* __restrict__ hhi_out, unsigned short* __restrict__ hlo_out,
    const float* __restrict__ xW, const float* __restrict__ bhh,
    float* __restrict__ bi, int tau)
{
    __shared__ unsigned short Bh[48][40], Bl[48][40];

    int t = threadIdx.x;
    int m0 = blockIdx.x * 96, j0 = blockIdx.y * 16;
    int w = t >> 6, lane = t & 63, kg = lane >> 4, r16 = lane & 15;

    f32x4 acc[2][3];   // [mi][gate]
#pragma unroll
    for (int i = 0; i < 2; i++)
#pragma unroll
        for (int j = 0; j < 3; j++)
#pragma unroll
            for (int q = 0; q < 4; q++) acc[i][j][q] = 0.f;

    // B staging role: thread t -> granule (row br, col bc8)
    int br = t >> 2, bc8 = (t & 3) * 8;
    long bsrc = (long)((br >> 4) * 1024 + j0 + (br & 15)) * 1024 + bc8;

    // A-direct per-lane fragment bases (row = batch, k-granule = kg*8)
    long arow0 = (long)(m0 + (w * 2 + 0) * 16 + r16) * 1024 + kg * 8;
    long arow1 = (long)(m0 + (w * 2 + 1) * 16 + r16) * 1024 + kg * 8;

    if (tau > 0) {
        for (int kt = 0; kt < 1024; kt += 32) {
            // stage B tile (48 rows x 32 k, hi+lo)
            *(short8*)&Bh[br][bc8] = *(const short8*)(Whi + bsrc + kt);
            *(short8*)&Bl[br][bc8] = *(const short8*)(Wlo + bsrc + kt);
            // A fragments direct from h (L2-resident)
            short8 ah0 = *(const short8*)(hhi_in + arow0 + kt);
            short8 al0 = *(const short8*)(hlo_in + arow0 + kt);
            short8 ah1 = *(const short8*)(hhi_in + arow1 + kt);
            short8 al1 = *(const short8*)(hlo_in + arow1 + kt);
            __syncthreads();
            short8 bh[3], bl2[3];
#pragma unroll
            for (int g = 0; g < 3; g++) {
                bh[g]  = *(short8*)&Bh[g * 16 + r16][kg * 8];
                bl2[g] = *(short8*)&Bl[g * 16 + r16][kg * 8];
            }
#pragma unroll
            for (int g = 0; g < 3; g++) {
                acc[0][g] = mfma16(ah0, bh[g],  acc[0][g]);
                acc[0][g] = mfma16(ah0, bl2[g], acc[0][g]);
                acc[0][g] = mfma16(al0, bh[g],  acc[0][g]);
                acc[1][g] = mfma16(ah1, bh[g],  acc[1][g]);
                acc[1][g] = mfma16(ah1, bl2[g], acc[1][g]);
                acc[1][g] = mfma16(al1, bh[g],  acc[1][g]);
            }
            __syncthreads();
        }
    }

    // epilogue: fully in-register gate fusion.
    // acc[mi][g] tile: row = m0 + (2w+mi)*16 + kg*4 + q ; col j = j0 + r16
    int j = j0 + r16;
    float b_r = bhh[j], b_z = bhh[1024 + j], b_n = bhh[2048 + j];
#pragma unroll
    for (int mi = 0; mi < 2; mi++) {
#pragma unroll
        for (int q = 0; q < 4; q++) {
            int b = m0 + (w * 2 + mi) * 16 + kg * 4 + q;
            int dir = (b >= 96) ? 1 : 0;
            int s = b - dir * 96;
            int pos = dir ? (95 - tau) : tau;
            const float* xp = xW + (long)(s * 96 + pos) * 3072;
            float r = sigmoidf_(xp[j] + acc[mi][0][q] + b_r);
            float z = sigmoidf_(xp[1024 + j] + acc[mi][1][q] + b_z);
            float n = tanhf(xp[2048 + j] + r * (acc[mi][2][q] + b_n));
            long o = (long)b * 1024 + j;
            float hprev = 0.f;
            if (tau > 0) hprev = bf2f(hhi_in[o]) + bf2f(hlo_in[o]);
            float hnew = (1.f - z) * n + z * hprev;
            unsigned short hh = f2bf(hnew);
            hhi_out[o] = hh;
            hlo_out[o] = f2bf(hnew - bf2f(hh));
            bi[(long)(s * 96 + pos) * 2048 + dir * 1024 + j] = hnew;
        }
    }
}

// ---------------- word attention ----------------
__global__ __launch_bounds__(256) void word_attn(
    const float* __restrict__ bi, const float* __restrict__ wctx,
    const float* __restrict__ wctx_b, float* __restrict__ sent_vecs)
{
    __shared__ float red[4];
    int s = blockIdx.x, t = threadIdx.x;
    int c = t * 8;
    float wc[8], accv[8];
#pragma unroll
    for (int i = 0; i < 8; i++) { wc[i] = wctx[c + i]; accv[i] = 0.f; }
    float bb = wctx_b[0];
    int lane = t & 63, w = t >> 6;

    for (int tok = 0; tok < 96; tok++) {
        const float* row = bi + (long)(s * 96 + tok) * 2048 + c;
        float v[8];
        float p = 0.f;
#pragma unroll
        for (int i = 0; i < 8; i++) { v[i] = row[i]; p += v[i] * wc[i]; }
        p += __shfl_xor(p, 32); p += __shfl_xor(p, 16); p += __shfl_xor(p, 8);
        p += __shfl_xor(p, 4);  p += __shfl_xor(p, 2);  p += __shfl_xor(p, 1);
        __syncthreads();
        if (lane == 0) red[w] = p;
        __syncthreads();
        float sc = expf(red[0] + red[1] + red[2] + red[3] + bb);
#pragma unroll
        for (int i = 0; i < 8; i++) accv[i] += sc * v[i];
    }
#pragma unroll
    for (int i = 0; i < 8; i++) sent_vecs[(long)s * 2048 + c + i] = accv[i];
}

// ---------------- sentence GRU step (f32 vector; batch 2; 4-way k-split) ----
__global__ __launch_bounds__(384) void sent_step(
    const float* __restrict__ Whh, const float* __restrict__ xWs,
    const float* __restrict__ sbhh, const float* __restrict__ hs_in,
    float* __restrict__ hs_out, float* __restrict__ sbi, int tau)
{
    __shared__ float sh[2][1024];
    __shared__ float gdot[3][16][2];
    int t = threadIdx.x, j0 = blockIdx.x * 16;

    for (int idx = t; idx < 2048; idx += 384)
        sh[idx >> 10][idx & 1023] = (tau > 0) ? hs_in[idx] : 0.f;
    __syncthreads();

    {
        int d = t >> 2, kq = t & 3;     // 96 dots x 4 k-quarters
        int rr = d >> 1, bq = d & 1;
        int gg = rr >> 4, jl = rr & 15;
        int wrow = gg * 1024 + j0 + jl;
        const float* wp = Whh + (long)wrow * 1024 + kq * 256;
        const float* hp = &sh[bq][kq * 256];
        float acc = 0.f;
        for (int k = 0; k < 256; k += 4) {
            f32x4 wv = *(const f32x4*)(wp + k);
            f32x4 hv = *(const f32x4*)(hp + k);
            acc += wv[0] * hv[0] + wv[1] * hv[1] + wv[2] * hv[2] + wv[3] * hv[3];
        }
        acc += __shfl_xor(acc, 1);
        acc += __shfl_xor(acc, 2);
        if (kq == 0) gdot[gg][jl][bq] = acc;
    }
    __syncthreads();

    if (t < 32) {
        int jl = t >> 1, bq = t & 1;
        int j = j0 + jl;
        int pos = bq ? (95 - tau) : tau;
        const float* xp = xWs + (long)pos * 3072;
        float r = sigmoidf_(xp[j] + gdot[0][jl][bq] + sbhh[j]);
        float z = sigmoidf_(xp[1024 + j] + gdot[1][jl][bq] + sbhh[1024 + j]);
        float n = tanhf(xp[2048 + j] + r * (gdot[2][jl][bq] + sbhh[2048 + j]));
        float hprev = (tau > 0) ? hs_in[bq * 1024 + j] : 0.f;
        float hnew = (1.f - z) * n + z * hprev;
        hs_out[bq * 1024 + j] = hnew;
        sbi[(long)pos * 2048 + bq * 1024 + j] = hnew;
    }
}

// ---------------- sentence attention ----------------
__global__ __launch_bounds__(256) void sent_scores(
    const float* __restrict__ sbi, const float* __restrict__ sctx,
    const float* __restrict__ sctx_b, float* __restrict__ scores)
{
    __shared__ float red[4];
    int s = blockIdx.x, t = threadIdx.x, c = t * 8;
    const float* row = sbi + (long)s * 2048 + c;
    float p = 0.f;
#pragma unroll
    for (int i = 0; i < 8; i++) p += row[i] * sctx[c + i];
    p += __shfl_xor(p, 32); p += __shfl_xor(p, 16); p += __shfl_xor(p, 8);
    p += __shfl_xor(p, 4);  p += __shfl_xor(p, 2);  p += __shfl_xor(p, 1);
    int lane = t & 63, w = t >> 6;
    if (lane == 0) red[w] = p;
    __syncthreads();
    if (t == 0) scores[s] = expf(red[0] + red[1] + red[2] + red[3] + sctx_b[0]);
}

__global__ __launch_bounds__(256) void doc_out(
    const float* __restrict__ sbi, const float* __restrict__ scores,
    float* __restrict__ out)
{
    int t = threadIdx.x, c = t * 8;
    float acc[8];
#pragma unroll
    for (int i = 0; i < 8; i++) acc[i] = 0.f;
    for (int s = 0; s < 96; s++) {
        float sc = scores[s];
        const float* row = sbi + (long)s * 2048 + c;
#pragma unroll
        for (int i = 0; i < 8; i++) acc[i] += sc * row[i];
    }
#pragma unroll
    for (int i = 0; i < 8; i++) out[c + i] = acc[i];
}

// ---------------- host ----------------
extern "C" void kernel_launch(void* const* d_in, const int* in_sizes, int n_in,
                              void* d_out, int out_size, void* d_ws, size_t ws_size,
                              hipStream_t stream)
{
    const int*   tokens    = (const int*)  d_in[0];
    const float* embedding = (const float*)d_in[1];
    const float* wWih = (const float*)d_in[2];
    const float* wWhh = (const float*)d_in[3];
    const float* wbih = (const float*)d_in[4];
    const float* wbhh = (const float*)d_in[5];
    const float* sWih = (const float*)d_in[6];
    const float* sWhh = (const float*)d_in[7];
    const float* sbih = (const float*)d_in[8];
    const float* sbhh = (const float*)d_in[9];
    const float* wctxw = (const float*)d_in[10];
    const float* wctxb = (const float*)d_in[11];
    const float* sctxw = (const float*)d_in[12];
    const float* sctxb = (const float*)d_in[13];
    float* out = (float*)d_out;

    char* p = (char*)d_ws;
    auto alloc = [&](size_t bytes) -> char* {
        char* r = p;
        p += (bytes + 255) & ~(size_t)255;
        return r;
    };
    unsigned short* WihHi  = (unsigned short*)alloc(3072l * 1024 * 2);
    unsigned short* WihLo  = (unsigned short*)alloc(3072l * 1024 * 2);
    unsigned short* WhhHi  = (unsigned short*)alloc(3072l * 1024 * 2);
    unsigned short* WhhLo  = (unsigned short*)alloc(3072l * 1024 * 2);
    unsigned short* sWihHi = (unsigned short*)alloc(3072l * 2048 * 2);
    unsigned short* sWihLo = (unsigned short*)alloc(3072l * 2048 * 2);
    float* xW        = (float*)alloc(9216l * 3072 * 4);
    float* bi        = (float*)alloc(9216l * 2048 * 4);
    unsigned short* hAhi = (unsigned short*)alloc(192l * 1024 * 2);
    unsigned short* hAlo = (unsigned short*)alloc(192l * 1024 * 2);
    unsigned short* hBhi = (unsigned short*)alloc(192l * 1024 * 2);
    unsigned short* hBlo = (unsigned short*)alloc(192l * 1024 * 2);
    float* sent_vecs = (float*)alloc(96l * 2048 * 4);
    float* xWs       = (float*)alloc(96l * 3072 * 4);
    float* hsA       = (float*)alloc(2l * 1024 * 4);
    float* hsB       = (float*)alloc(2l * 1024 * 4);
    float* sbi       = (float*)alloc(96l * 2048 * 4);
    float* scores    = (float*)alloc(512);
    (void)ws_size; (void)in_sizes; (void)n_in; (void)out_size;

    split_f32<<<1024, 256, 0, stream>>>(wWih, WihHi, WihLo, 3072 * 1024);
    split_f32<<<1024, 256, 0, stream>>>(wWhh, WhhHi, WhhLo, 3072 * 1024);
    split_f32<<<1024, 256, 0, stream>>>(sWih, sWihHi, sWihLo, 3072 * 2048);

    gemm_split<<<dim3(144, 24), 256, 0, stream>>>(
        embedding, tokens, WihHi, WihLo, wbih, xW, 9216, 3072, 1024);

    for (int tau = 0; tau < 96; tau++) {
        const unsigned short *hi_in, *lo_in;
        unsigned short *hi_out, *lo_out;
        if (tau & 1) { hi_in = hAhi; lo_in = hAlo; hi_out = hBhi; lo_out = hBlo; }
        else         { hi_in = hBhi; lo_in = hBlo; hi_out = hAhi; lo_out = hAlo; }
        word_step2<<<dim3(2, 64), 192, 0, stream>>>(
            WhhHi, WhhLo, hi_in, lo_in, hi_out, lo_out, xW, wbhh, bi, tau);
    }

    word_attn<<<96, 256, 0, stream>>>(bi, wctxw, wctxb, sent_vecs);

    gemm_split<<<dim3(2, 24), 256, 0, stream>>>(
        sent_vecs, nullptr, sWihHi, sWihLo, sbih, xWs, 96, 3072, 2048);

    for (int tau = 0; tau < 96; tau++) {
        const float* hin; float* hout;
        if (tau & 1) { hin = hsA; hout = hsB; }
        else         { hin = hsB; hout = hsA; }
        sent_step<<<64, 384, 0, stream>>>(sWhh, xWs, sbhh, hin, hout, sbi, tau);
    }

    sent_scores<<<96, 256, 0, stream>>>(sbi, sctxw, sctxb, scores);
    doc_out<<<1, 256, 0, stream>>>(sbi, scores, out);
}